// Round 3
// baseline (177.666 us; speedup 1.0000x reference)
//
#include <hip/hip_runtime.h>
#include <hip/hip_bf16.h>

#define Bdim 512
#define Sdim 50
#define Hdim 512
#define Ndim 20000
#define Kdim2 1024   // 2*H
#define SEENW 640    // u32 words per row for the seen-bitmask (20000 bits -> 625, pad 640)

typedef __bf16 bf16x8 __attribute__((ext_vector_type(8)));
typedef float f32x4 __attribute__((ext_vector_type(4)));
typedef unsigned short u16;

__device__ __forceinline__ u16 f2bf(float f) {
  unsigned u = __builtin_bit_cast(unsigned, f);
  u = (u + 0x7fffu + ((u >> 16) & 1u)) >> 16;   // RNE
  return (u16)u;
}
__device__ __forceinline__ float bf2f(u16 v) {
  unsigned u = ((unsigned)v) << 16;
  return __builtin_bit_cast(float, u);
}

// ---------------- merged cast (E_w then all_memory) ----------------
__global__ __launch_bounds__(256) void cast2_kernel(const float* __restrict__ a, u16* __restrict__ da, int n4a,
                                                    const float* __restrict__ b, u16* __restrict__ db, int n4b) {
  int stride = gridDim.x * blockDim.x;
  int ntot = n4a + n4b;
  for (int i = blockIdx.x * blockDim.x + threadIdx.x; i < ntot; i += stride) {
    const float4* src; ushort4* dst; int j;
    if (i < n4a) { src = reinterpret_cast<const float4*>(a); dst = reinterpret_cast<ushort4*>(da); j = i; }
    else         { src = reinterpret_cast<const float4*>(b); dst = reinterpret_cast<ushort4*>(db); j = i - n4a; }
    float4 v = src[j];
    ushort4 o;
    o.x = f2bf(v.x); o.y = f2bf(v.y); o.z = f2bf(v.z); o.w = f2bf(v.w);
    dst[j] = o;
  }
}

// ---------------- prep: cast last_memory/W_w/U_w + zero scores/lm/seen ----------
// scores/lm are atomic-accumulated and seen is atomicOr'd -> must be zeroed
// EVERY call (graph replays don't re-poison). V_b dropped: softmax is
// shift-invariant, a constant bias on all scores of a row cancels.
__global__ __launch_bounds__(256) void prep_kernel(const float* __restrict__ a, u16* __restrict__ da,
                                                   const float* __restrict__ b, u16* __restrict__ db,
                                                   const float* __restrict__ c, u16* __restrict__ dc,
                                                   float* __restrict__ scores, float* __restrict__ lm,
                                                   unsigned* __restrict__ seen) {
  int i = blockIdx.x * blockDim.x + threadIdx.x;   // 65536 threads, one float4 each
  float4 v; ushort4 o;
  v = reinterpret_cast<const float4*>(a)[i];
  o.x = f2bf(v.x); o.y = f2bf(v.y); o.z = f2bf(v.z); o.w = f2bf(v.w);
  reinterpret_cast<ushort4*>(da)[i] = o;
  v = reinterpret_cast<const float4*>(b)[i];
  o.x = f2bf(v.x); o.y = f2bf(v.y); o.z = f2bf(v.z); o.w = f2bf(v.w);
  reinterpret_cast<ushort4*>(db)[i] = o;
  v = reinterpret_cast<const float4*>(c)[i];
  o.x = f2bf(v.x); o.y = f2bf(v.y); o.z = f2bf(v.z); o.w = f2bf(v.w);
  reinterpret_cast<ushort4*>(dc)[i] = o;
  int stride = gridDim.x * blockDim.x;
  for (int j = i; j < Bdim * Sdim; j += stride) scores[j] = 0.f;
  for (int j = i; j < Bdim * Hdim; j += stride) lm[j] = 0.f;
  for (int j = i; j < Bdim * SEENW; j += stride) seen[j] = 0u;
}

// ---------------- seen-item scatter ----------------
__global__ __launch_bounds__(256) void scatter_kernel(const int* __restrict__ iseq,
                                                      unsigned* __restrict__ seen) {
  int i = blockIdx.x * blockDim.x + threadIdx.x;
  if (i < Bdim * Sdim) {
    int b = i / Sdim;
    int it = iseq[i];
    if (it > 0) atomicOr(&seen[b * SEENW + (it >> 5)], 1u << (it & 31));
  }
}

// ---------------- softmax over S + context readout -> feat (bf16) ----------------
__global__ __launch_bounds__(256) void softmax_ctx_kernel(
    const float* __restrict__ scores, const unsigned char* __restrict__ mask,
    const u16* __restrict__ amB, const float* __restrict__ last_memory,
    u16* __restrict__ feat) {
  int b = blockIdx.x;
  __shared__ float alpha[Sdim];
  int tid = threadIdx.x;
  if (tid < 64) {
    float s = -1e30f;
    if (tid < Sdim) {
      s = scores[b * Sdim + tid];
      if (mask[b * Sdim + tid]) s = -1e9f;   // mask is all-false in this problem
    }
    float m = s;
#pragma unroll
    for (int off = 32; off; off >>= 1) m = fmaxf(m, __shfl_xor(m, off));
    float e = (tid < Sdim) ? __expf(s - m) : 0.f;
    float sum = e;
#pragma unroll
    for (int off = 32; off; off >>= 1) sum += __shfl_xor(sum, off);
    if (tid < Sdim) alpha[tid] = e / sum;
  }
  __syncthreads();
  for (int h = tid; h < Hdim; h += 256) {
    const u16* amp = amB + ((long)b * Sdim) * Hdim + h;
    float c = 0.f;
#pragma unroll 5
    for (int s = 0; s < Sdim; ++s) c += alpha[s] * bf2f(amp[(long)s * Hdim]);
    feat[b * Kdim2 + h] = f2bf(c);
    feat[b * Kdim2 + Hdim + h] = f2bf(last_memory[b * Hdim + h]);
  }
}

// ---------------- MFMA GEMM, B-transposed layout (A: MxK, Bmat: NxK, both bf16) ----
// 4-slot LDS ring + counted vmcnt (T4): stage tile kt+3 each iteration, wait
// s_waitcnt vmcnt(12) (3 tiles x 4 loads stay in flight), raw s_barrier (no
// compiler vmcnt(0) drain). Slot kt&3 is only overwritten by the stage issued
// at iteration kt+1, which is after iteration kt's trailing barrier.
// EPI 0: atomicAdd f32 into out (M x N), split-K via gridDim.z, 3-D grid, no swizzle
// EPI 1: scores[r] += sum_c V[c]*tanh(acc + lm[b,c]); 1-D grid, XCD swizzle
//        groups the 4 n-tiles of one m-panel per XCD (A-panel L2 reuse)
// EPI 2: out = seen ? 0 : sigmoid(acc); 1-D grid, XCD swizzle groups the 4
//        m-tiles of one E_w n-panel per XCD (E-panel L2 reuse)
#define BM 128
#define BN 128
#define BK 32

template <int EPI>
__global__ __launch_bounds__(256) void gemm_bt(
    const u16* __restrict__ A, const u16* __restrict__ Bmat,
    int M, int N, int K,
    float* __restrict__ out,
    const float* __restrict__ lm, const float* __restrict__ Vw,
    float* __restrict__ scores, const unsigned* __restrict__ seen) {
  __shared__ bf16x8 Asl[4][BM * BK / 8];   // 4-slot ring, 8 KB per slot per matrix
  __shared__ bf16x8 Bsl[4][BN * BK / 8];
  const int tid = threadIdx.x;
  const int lane = tid & 63;
  const int wid = tid >> 6;
  const int wr = wid >> 1, wc = wid & 1;      // 2x2 wave grid, 64x64 per wave
  const int la = lane & 15, lb = lane >> 4;

  int bx, by, kt0, kt1;
  if constexpr (EPI == 0) {
    bx = blockIdx.x; by = blockIdx.y;
    int ktotal = K / BK; int kper = ktotal / gridDim.z;
    kt0 = blockIdx.z * kper; kt1 = kt0 + kper;
  } else {
    // m204 bijective XCD swizzle: blocks bid%8==x run on XCD x; give each XCD
    // a contiguous wgid chunk, then wgid groups 4 co-panel tiles together.
    int nwg = gridDim.x, bid = blockIdx.x;
    int q = nwg >> 3, r = nwg & 7;
    int x = bid & 7, i = bid >> 3;
    int wgid = (x < r ? x * (q + 1) : r * (q + 1) + (x - r) * q) + i;
    if constexpr (EPI == 1) { by = wgid >> 2; bx = wgid & 3; }
    else                    { bx = wgid >> 2; by = wgid & 3; }
    kt0 = 0; kt1 = K / BK;
  }
  const int m0 = by * BM;
  const int n0 = bx * BN;

  f32x4 acc[4][4];
  const f32x4 zero = {0.f, 0.f, 0.f, 0.f};
#pragma unroll
  for (int i = 0; i < 4; ++i)
#pragma unroll
    for (int j = 0; j < 4; ++j) acc[i][j] = zero;

  // staging: 512 chunks of 16B per tile; thread handles chunks tid and tid+256
  const int c1 = tid + 256;
  const int r0 = tid >> 2, e0 = (tid & 3) * 8;
  const int r1 = c1 >> 2, e1 = (c1 & 3) * 8;
  // clamp B rows for the partial last n-tile (EPI2); harmless elsewhere
  int br0 = n0 + r0; if (br0 > N - 1) br0 = N - 1;
  int br1 = n0 + r1; if (br1 > N - 1) br1 = N - 1;
  const u16* gA0 = A + (long)(m0 + r0) * K + e0;
  const u16* gA1 = A + (long)(m0 + r1) * K + e1;
  const u16* gB0 = Bmat + (long)br0 * K + e0;
  const u16* gB1 = Bmat + (long)br1 * K + e1;

  auto STAGE = [&](int slot, int kt) {
    const int k0 = kt * BK;
    __builtin_amdgcn_global_load_lds((const __attribute__((address_space(1))) void*)(gA0 + k0),
                                     (__attribute__((address_space(3))) void*)(void*)&Asl[slot][wid * 64], 16, 0, 0);
    __builtin_amdgcn_global_load_lds((const __attribute__((address_space(1))) void*)(gA1 + k0),
                                     (__attribute__((address_space(3))) void*)(void*)&Asl[slot][256 + wid * 64], 16, 0, 0);
    __builtin_amdgcn_global_load_lds((const __attribute__((address_space(1))) void*)(gB0 + k0),
                                     (__attribute__((address_space(3))) void*)(void*)&Bsl[slot][wid * 64], 16, 0, 0);
    __builtin_amdgcn_global_load_lds((const __attribute__((address_space(1))) void*)(gB1 + k0),
                                     (__attribute__((address_space(3))) void*)(void*)&Bsl[slot][256 + wid * 64], 16, 0, 0);
  };

  // prologue: 3 tiles in flight (12 vm events/wave)
  STAGE(kt0 & 3, kt0);
  STAGE((kt0 + 1) & 3, (kt0 + 1 < kt1) ? kt0 + 1 : kt1 - 1);
  STAGE((kt0 + 2) & 3, (kt0 + 2 < kt1) ? kt0 + 2 : kt1 - 1);

  for (int kt = kt0; kt < kt1; ++kt) {
    int pf = kt + 3;
    STAGE(pf & 3, (pf < kt1) ? pf : kt1 - 1);   // uniform 4 loads/iter keeps vmcnt math exact
    asm volatile("s_waitcnt vmcnt(12)" ::: "memory");   // tile kt's 4 loads landed
    __builtin_amdgcn_s_barrier();                        // all waves' loads landed
    __builtin_amdgcn_sched_barrier(0);
    const int sl = kt & 3;
    bf16x8 af[4], bfr[4];
#pragma unroll
    for (int mi = 0; mi < 4; ++mi)
      af[mi] = Asl[sl][(wr * 64 + mi * 16 + la) * 4 + lb];   // A[row][k-chunk lb]
#pragma unroll
    for (int ni = 0; ni < 4; ++ni)
      bfr[ni] = Bsl[sl][(wc * 64 + ni * 16 + la) * 4 + lb];  // B[ncol][k-chunk lb]
#pragma unroll
    for (int mi = 0; mi < 4; ++mi)
#pragma unroll
      for (int ni = 0; ni < 4; ++ni)
        acc[mi][ni] = __builtin_amdgcn_mfma_f32_16x16x32_bf16(af[mi], bfr[ni], acc[mi][ni], 0, 0, 0);
    __builtin_amdgcn_sched_barrier(0);
    __builtin_amdgcn_s_barrier();               // all waves done reading slot kt&3
  }
  asm volatile("s_waitcnt vmcnt(0)" ::: "memory");   // drain tail stages before exit

  // C/D layout (verified): col = lane&15, row = (lane>>4)*4 + reg
  if constexpr (EPI == 0) {
#pragma unroll
    for (int mi = 0; mi < 4; ++mi)
#pragma unroll
      for (int i = 0; i < 4; ++i) {
        int r = m0 + wr * 64 + mi * 16 + lb * 4 + i;
#pragma unroll
        for (int ni = 0; ni < 4; ++ni) {
          int c = n0 + wc * 64 + ni * 16 + la;
          atomicAdd(&out[(long)r * N + c], acc[mi][ni][i]);
        }
      }
  }
  if constexpr (EPI == 1) {
#pragma unroll
    for (int mi = 0; mi < 4; ++mi)
#pragma unroll
      for (int i = 0; i < 4; ++i) {
        int r = m0 + wr * 64 + mi * 16 + lb * 4 + i;
        int bidx = r / Sdim;
        float p = 0.f;
#pragma unroll
        for (int ni = 0; ni < 4; ++ni) {
          int c = n0 + wc * 64 + ni * 16 + la;
          float x = acc[mi][ni][i] + lm[bidx * Hdim + c];
          x = fminf(fmaxf(x, -9.f), 9.f);           // tanh saturates; avoid inf/inf
          float e = __expf(2.f * x);
          p += Vw[c] * ((e - 1.f) / (e + 1.f));
        }
        p += __shfl_xor(p, 1);
        p += __shfl_xor(p, 2);
        p += __shfl_xor(p, 4);
        p += __shfl_xor(p, 8);
        if (la == 0) atomicAdd(&scores[r], p);
      }
  }
  if constexpr (EPI == 2) {
#pragma unroll
    for (int mi = 0; mi < 4; ++mi)
#pragma unroll
      for (int i = 0; i < 4; ++i) {
        int r = m0 + wr * 64 + mi * 16 + lb * 4 + i;
        long rb = (long)r * Ndim;
#pragma unroll
        for (int ni = 0; ni < 4; ++ni) {
          int c = n0 + wc * 64 + ni * 16 + la;
          if (c < Ndim) {
            unsigned wbits = seen[r * SEENW + (c >> 5)];
            float val = 0.f;
            if (!((wbits >> (c & 31)) & 1u))
              val = 1.f / (1.f + __expf(-acc[mi][ni][i]));
            out[rb + c] = val;
          }
        }
      }
  }
}

// ---------------- launcher ----------------
extern "C" void kernel_launch(void* const* d_in, const int* in_sizes, int n_in,
                              void* d_out, int out_size, void* d_ws, size_t ws_size,
                              hipStream_t stream) {
  (void)in_sizes; (void)n_in; (void)out_size; (void)ws_size;
  const float* all_memory  = (const float*)d_in[0];
  const float* last_memory = (const float*)d_in[1];
  const int*   item_seq    = (const int*)d_in[2];
  const unsigned char* mask = (const unsigned char*)d_in[3];
  const float* U_w = (const float*)d_in[4];
  const float* W_w = (const float*)d_in[5];
  const float* V_w = (const float*)d_in[6];
  const float* E_w = (const float*)d_in[8];
  float* out = (float*)d_out;

  char* w = (char*)d_ws;
  u16* wsE    = (u16*)w; w += (size_t)Ndim * Kdim2 * 2;         // 40.96 MB
  u16* wsA    = (u16*)w; w += (size_t)Bdim * Sdim * Hdim * 2;   // 26.2 MB
  u16* wsFeat = (u16*)w; w += (size_t)Bdim * Kdim2 * 2;         // 1 MB
  u16* wsLast = (u16*)w; w += (size_t)Hdim * Hdim * 2;          // 0.5 MB
  u16* wsW    = (u16*)w; w += (size_t)Hdim * Hdim * 2;
  u16* wsU    = (u16*)w; w += (size_t)Hdim * Hdim * 2;
  float* wsLm     = (float*)w; w += (size_t)Bdim * Hdim * 4;    // 1 MB
  float* wsScores = (float*)w; w += (size_t)Bdim * Sdim * 4;
  unsigned* wsSeen = (unsigned*)w; w += (size_t)Bdim * SEENW * 4;

  prep_kernel<<<256, 256, 0, stream>>>(last_memory, wsLast, W_w, wsW, U_w, wsU,
                                       wsScores, wsLm, wsSeen);
  scatter_kernel<<<100, 256, 0, stream>>>(item_seq, wsSeen);
  cast2_kernel<<<4096, 256, 0, stream>>>(E_w, wsE, Ndim * Kdim2 / 4,
                                         all_memory, wsA, Bdim * Sdim * Hdim / 4);

  // lm = last_memory @ W_w^T   (512x512x512, split-K=4, atomic accumulate)
  gemm_bt<0><<<dim3(Hdim / BN, Bdim / BM, 4), 256, 0, stream>>>(
      wsLast, wsW, Bdim, Hdim, Hdim, wsLm, nullptr, nullptr, nullptr, nullptr);
  // scores += sum_k V[k]*tanh(am + lm)   (25600x512x512), 1-D grid 800 blocks
  gemm_bt<1><<<dim3((Bdim * Sdim / BM) * (Hdim / BN)), 256, 0, stream>>>(
      wsA, wsU, Bdim * Sdim, Hdim, Hdim, nullptr, wsLm, V_w, wsScores, nullptr);
  softmax_ctx_kernel<<<Bdim, 256, 0, stream>>>(wsScores, mask, wsA, last_memory, wsFeat);
  // out = sigmoid/mask( feat @ E_w^T )   (512x20000x1024), 1-D grid 628 blocks
  gemm_bt<2><<<dim3(((Ndim + BN - 1) / BN) * (Bdim / BM)), 256, 0, stream>>>(
      wsFeat, wsE, Bdim, Ndim, Kdim2, out, nullptr, nullptr, nullptr, wsSeen);
}

// Round 4
// 141.342 us; speedup vs baseline: 1.2570x; 1.2570x over previous
//
#include <hip/hip_runtime.h>
#include <hip/hip_bf16.h>

#define Bdim 512
#define Sdim 50
#define Hdim 512
#define Ndim 20000
#define Kdim2 1024   // 2*H
#define SEENW 640    // u32 words per row for the seen-bitmask (20000 bits -> 625, pad 640)

typedef __bf16 bf16x8 __attribute__((ext_vector_type(8)));
typedef float f32x4 __attribute__((ext_vector_type(4)));
typedef unsigned short u16;

__device__ __forceinline__ u16 f2bf(float f) {
  unsigned u = __builtin_bit_cast(unsigned, f);
  u = (u + 0x7fffu + ((u >> 16) & 1u)) >> 16;   // RNE
  return (u16)u;
}
__device__ __forceinline__ float bf2f(u16 v) {
  unsigned u = ((unsigned)v) << 16;
  return __builtin_bit_cast(float, u);
}

// ---------------- merged cast (E_w then all_memory) ----------------
__global__ __launch_bounds__(256) void cast2_kernel(const float* __restrict__ a, u16* __restrict__ da, int n4a,
                                                    const float* __restrict__ b, u16* __restrict__ db, int n4b) {
  int stride = gridDim.x * blockDim.x;
  int ntot = n4a + n4b;
  for (int i = blockIdx.x * blockDim.x + threadIdx.x; i < ntot; i += stride) {
    const float4* src; ushort4* dst; int j;
    if (i < n4a) { src = reinterpret_cast<const float4*>(a); dst = reinterpret_cast<ushort4*>(da); j = i; }
    else         { src = reinterpret_cast<const float4*>(b); dst = reinterpret_cast<ushort4*>(db); j = i - n4a; }
    float4 v = src[j];
    ushort4 o;
    o.x = f2bf(v.x); o.y = f2bf(v.y); o.z = f2bf(v.z); o.w = f2bf(v.w);
    dst[j] = o;
  }
}

// ---------------- prep: cast last_memory/W_w/U_w + zero scores/lm/seen ----------
// scores/lm are atomic-accumulated and seen is atomicOr'd -> must be zeroed
// EVERY call (graph replays don't re-poison). V_b dropped: softmax is
// shift-invariant, a constant bias on all scores of a row cancels.
__global__ __launch_bounds__(256) void prep_kernel(const float* __restrict__ a, u16* __restrict__ da,
                                                   const float* __restrict__ b, u16* __restrict__ db,
                                                   const float* __restrict__ c, u16* __restrict__ dc,
                                                   float* __restrict__ scores, float* __restrict__ lm,
                                                   unsigned* __restrict__ seen) {
  int i = blockIdx.x * blockDim.x + threadIdx.x;   // 65536 threads, one float4 each
  float4 v; ushort4 o;
  v = reinterpret_cast<const float4*>(a)[i];
  o.x = f2bf(v.x); o.y = f2bf(v.y); o.z = f2bf(v.z); o.w = f2bf(v.w);
  reinterpret_cast<ushort4*>(da)[i] = o;
  v = reinterpret_cast<const float4*>(b)[i];
  o.x = f2bf(v.x); o.y = f2bf(v.y); o.z = f2bf(v.z); o.w = f2bf(v.w);
  reinterpret_cast<ushort4*>(db)[i] = o;
  v = reinterpret_cast<const float4*>(c)[i];
  o.x = f2bf(v.x); o.y = f2bf(v.y); o.z = f2bf(v.z); o.w = f2bf(v.w);
  reinterpret_cast<ushort4*>(dc)[i] = o;
  int stride = gridDim.x * blockDim.x;
  for (int j = i; j < Bdim * Sdim; j += stride) scores[j] = 0.f;
  for (int j = i; j < Bdim * Hdim; j += stride) lm[j] = 0.f;
  for (int j = i; j < Bdim * SEENW; j += stride) seen[j] = 0u;
}

// ---------------- seen-item scatter ----------------
__global__ __launch_bounds__(256) void scatter_kernel(const int* __restrict__ iseq,
                                                      unsigned* __restrict__ seen) {
  int i = blockIdx.x * blockDim.x + threadIdx.x;
  if (i < Bdim * Sdim) {
    int b = i / Sdim;
    int it = iseq[i];
    if (it > 0) atomicOr(&seen[b * SEENW + (it >> 5)], 1u << (it & 31));
  }
}

// ---------------- softmax over S + context readout -> feat (bf16) ----------------
__global__ __launch_bounds__(256) void softmax_ctx_kernel(
    const float* __restrict__ scores, const unsigned char* __restrict__ mask,
    const u16* __restrict__ amB, const float* __restrict__ last_memory,
    u16* __restrict__ feat) {
  int b = blockIdx.x;
  __shared__ float alpha[Sdim];
  int tid = threadIdx.x;
  if (tid < 64) {
    float s = -1e30f;
    if (tid < Sdim) {
      s = scores[b * Sdim + tid];
      if (mask[b * Sdim + tid]) s = -1e9f;   // mask is all-false in this problem
    }
    float m = s;
#pragma unroll
    for (int off = 32; off; off >>= 1) m = fmaxf(m, __shfl_xor(m, off));
    float e = (tid < Sdim) ? __expf(s - m) : 0.f;
    float sum = e;
#pragma unroll
    for (int off = 32; off; off >>= 1) sum += __shfl_xor(sum, off);
    if (tid < Sdim) alpha[tid] = e / sum;
  }
  __syncthreads();
  for (int h = tid; h < Hdim; h += 256) {
    const u16* amp = amB + ((long)b * Sdim) * Hdim + h;
    float c = 0.f;
#pragma unroll 5
    for (int s = 0; s < Sdim; ++s) c += alpha[s] * bf2f(amp[(long)s * Hdim]);
    feat[b * Kdim2 + h] = f2bf(c);
    feat[b * Kdim2 + Hdim + h] = f2bf(last_memory[b * Hdim + h]);
  }
}

// ---------------- MFMA GEMM, B-transposed layout (A: MxK, Bmat: NxK, both bf16) ----
// 256x128 tile, BK=32, 512 threads = 8 waves (4M x 2N), per-wave 64x64 output.
// 2-phase double-buffered LDS (proven round-2 schedule): issue next tile's
// global_load_lds BEFORE computing current tile; one __syncthreads per K-step.
// Bigger tile amortizes the per-iteration fixed cost (barrier+drain+latency):
// ~1024 MFMA-cyc/iter/block vs ~1000 cyc fixed, vs 25% duty at 128x128.
// EPI 0: atomicAdd f32 into out (M x N), split-K via gridDim.z, 3-D grid
// EPI 1: scores[r] += sum_c V[c]*tanh(acc + lm[b,c]); 1-D grid, XCD swizzle
//        groups the 4 n-tiles of one A m-panel per XCD (A-panel L2 reuse)
// EPI 2: out = seen ? 0 : sigmoid(acc); 1-D grid, XCD swizzle groups the 2
//        m-tiles of one E_w n-panel per XCD (E-panel L2 reuse)
#define BM 256
#define BN 128
#define BK 32

template <int EPI>
__global__ __launch_bounds__(512, 4) void gemm_bt(
    const u16* __restrict__ A, const u16* __restrict__ Bmat,
    int M, int N, int K,
    float* __restrict__ out,
    const float* __restrict__ lm, const float* __restrict__ Vw,
    float* __restrict__ scores, const unsigned* __restrict__ seen) {
  __shared__ bf16x8 Asl[2][BM * BK / 8];   // 2 x 1024 chunks of 16B = 32 KB
  __shared__ bf16x8 Bsl[2][BN * BK / 8];   // 2 x  512 chunks of 16B = 16 KB
  const int tid = threadIdx.x;
  const int lane = tid & 63;
  const int wid = tid >> 6;                 // 0..7
  const int wr = wid >> 1, wc = wid & 1;    // 4x2 wave grid, 64x64 per wave
  const int la = lane & 15, lb = lane >> 4;

  int bx, by, kt0, kt1;
  if constexpr (EPI == 0) {
    bx = blockIdx.x; by = blockIdx.y;
    int ktotal = K / BK; int kper = ktotal / gridDim.z;
    kt0 = blockIdx.z * kper; kt1 = kt0 + kper;
  } else {
    // m204 bijective XCD swizzle: contiguous wgid chunk per XCD; wgid groups
    // co-panel tiles together so panel re-reads are same-XCD L2 hits.
    int nwg = gridDim.x, bid = blockIdx.x;
    int q = nwg >> 3, r = nwg & 7;
    int x = bid & 7, i = bid >> 3;
    int wgid = (x < r ? x * (q + 1) : r * (q + 1) + (x - r) * q) + i;
    if constexpr (EPI == 1) { by = wgid >> 2; bx = wgid & 3; }   // 4 n-tiles/panel
    else                    { bx = wgid >> 1; by = wgid & 1; }   // 2 m-tiles/panel
    kt0 = 0; kt1 = K / BK;
  }
  const int m0 = by * BM;
  const int n0 = bx * BN;

  f32x4 acc[4][4];
  const f32x4 zero = {0.f, 0.f, 0.f, 0.f};
#pragma unroll
  for (int i = 0; i < 4; ++i)
#pragma unroll
    for (int j = 0; j < 4; ++j) acc[i][j] = zero;

  // staging: A = 1024 chunks of 16B (rows 0..255), B = 512 chunks (rows 0..127)
  // thread t handles A chunks t, t+512 and B chunk t.
  const int rA0 = tid >> 2, eA = (tid & 3) * 8;      // A rows 0..127
  const int rA1 = 128 + (tid >> 2);                  // A rows 128..255
  int brB = n0 + (tid >> 2); if (brB > N - 1) brB = N - 1;   // clamp last n-tile
  const u16* gA0 = A + (long)(m0 + rA0) * K + eA;
  const u16* gA1 = A + (long)(m0 + rA1) * K + eA;
  const u16* gB  = Bmat + (long)brB * K + eA;

  auto STAGE = [&](int buf, int kt) {
    const int k0 = kt * BK;
    __builtin_amdgcn_global_load_lds((const __attribute__((address_space(1))) void*)(gA0 + k0),
                                     (__attribute__((address_space(3))) void*)(void*)&Asl[buf][wid * 64], 16, 0, 0);
    __builtin_amdgcn_global_load_lds((const __attribute__((address_space(1))) void*)(gA1 + k0),
                                     (__attribute__((address_space(3))) void*)(void*)&Asl[buf][512 + wid * 64], 16, 0, 0);
    __builtin_amdgcn_global_load_lds((const __attribute__((address_space(1))) void*)(gB + k0),
                                     (__attribute__((address_space(3))) void*)(void*)&Bsl[buf][wid * 64], 16, 0, 0);
  };

  STAGE(0, kt0);
  __syncthreads();          // drain + barrier: buf0 ready
  int cur = 0;
  for (int kt = kt0; kt < kt1; ++kt) {
    if (kt + 1 < kt1) STAGE(cur ^ 1, kt + 1);   // issue next tile early

    bf16x8 af[4], bfr[4];
#pragma unroll
    for (int mi = 0; mi < 4; ++mi)
      af[mi] = Asl[cur][(wr * 64 + mi * 16 + la) * 4 + lb];   // A[row][k-chunk lb]
#pragma unroll
    for (int ni = 0; ni < 4; ++ni)
      bfr[ni] = Bsl[cur][(wc * 64 + ni * 16 + la) * 4 + lb];  // B[ncol][k-chunk lb]
#pragma unroll
    for (int mi = 0; mi < 4; ++mi)
#pragma unroll
      for (int ni = 0; ni < 4; ++ni)
        acc[mi][ni] = __builtin_amdgcn_mfma_f32_16x16x32_bf16(af[mi], bfr[ni], acc[mi][ni], 0, 0, 0);
    __syncthreads();        // one barrier per K-step; drains the new stage too
    cur ^= 1;
  }

  // C/D layout (verified): col = lane&15, row = (lane>>4)*4 + reg
  if constexpr (EPI == 0) {
#pragma unroll
    for (int mi = 0; mi < 4; ++mi)
#pragma unroll
      for (int i = 0; i < 4; ++i) {
        int r = m0 + wr * 64 + mi * 16 + lb * 4 + i;
#pragma unroll
        for (int ni = 0; ni < 4; ++ni) {
          int c = n0 + wc * 64 + ni * 16 + la;
          atomicAdd(&out[(long)r * N + c], acc[mi][ni][i]);
        }
      }
  }
  if constexpr (EPI == 1) {
#pragma unroll
    for (int mi = 0; mi < 4; ++mi)
#pragma unroll
      for (int i = 0; i < 4; ++i) {
        int r = m0 + wr * 64 + mi * 16 + lb * 4 + i;
        int bidx = r / Sdim;
        float p = 0.f;
#pragma unroll
        for (int ni = 0; ni < 4; ++ni) {
          int c = n0 + wc * 64 + ni * 16 + la;
          float x = acc[mi][ni][i] + lm[bidx * Hdim + c];
          x = fminf(fmaxf(x, -9.f), 9.f);           // tanh saturates; avoid inf/inf
          float e = __expf(2.f * x);
          p += Vw[c] * ((e - 1.f) / (e + 1.f));
        }
        p += __shfl_xor(p, 1);
        p += __shfl_xor(p, 2);
        p += __shfl_xor(p, 4);
        p += __shfl_xor(p, 8);
        if (la == 0) atomicAdd(&scores[r], p);
      }
  }
  if constexpr (EPI == 2) {
#pragma unroll
    for (int mi = 0; mi < 4; ++mi)
#pragma unroll
      for (int i = 0; i < 4; ++i) {
        int r = m0 + wr * 64 + mi * 16 + lb * 4 + i;
        long rb = (long)r * Ndim;
#pragma unroll
        for (int ni = 0; ni < 4; ++ni) {
          int c = n0 + wc * 64 + ni * 16 + la;
          if (c < Ndim) {
            unsigned wbits = seen[r * SEENW + (c >> 5)];
            float val = 0.f;
            if (!((wbits >> (c & 31)) & 1u))
              val = 1.f / (1.f + __expf(-acc[mi][ni][i]));
            out[rb + c] = val;
          }
        }
      }
  }
}

// ---------------- launcher ----------------
extern "C" void kernel_launch(void* const* d_in, const int* in_sizes, int n_in,
                              void* d_out, int out_size, void* d_ws, size_t ws_size,
                              hipStream_t stream) {
  (void)in_sizes; (void)n_in; (void)out_size; (void)ws_size;
  const float* all_memory  = (const float*)d_in[0];
  const float* last_memory = (const float*)d_in[1];
  const int*   item_seq    = (const int*)d_in[2];
  const unsigned char* mask = (const unsigned char*)d_in[3];
  const float* U_w = (const float*)d_in[4];
  const float* W_w = (const float*)d_in[5];
  const float* V_w = (const float*)d_in[6];
  const float* E_w = (const float*)d_in[8];
  float* out = (float*)d_out;

  char* w = (char*)d_ws;
  u16* wsE    = (u16*)w; w += (size_t)Ndim * Kdim2 * 2;         // 40.96 MB
  u16* wsA    = (u16*)w; w += (size_t)Bdim * Sdim * Hdim * 2;   // 26.2 MB
  u16* wsFeat = (u16*)w; w += (size_t)Bdim * Kdim2 * 2;         // 1 MB
  u16* wsLast = (u16*)w; w += (size_t)Hdim * Hdim * 2;          // 0.5 MB
  u16* wsW    = (u16*)w; w += (size_t)Hdim * Hdim * 2;
  u16* wsU    = (u16*)w; w += (size_t)Hdim * Hdim * 2;
  float* wsLm     = (float*)w; w += (size_t)Bdim * Hdim * 4;    // 1 MB
  float* wsScores = (float*)w; w += (size_t)Bdim * Sdim * 4;
  unsigned* wsSeen = (unsigned*)w; w += (size_t)Bdim * SEENW * 4;

  prep_kernel<<<256, 256, 0, stream>>>(last_memory, wsLast, W_w, wsW, U_w, wsU,
                                       wsScores, wsLm, wsSeen);
  scatter_kernel<<<100, 256, 0, stream>>>(item_seq, wsSeen);
  cast2_kernel<<<4096, 256, 0, stream>>>(E_w, wsE, Ndim * Kdim2 / 4,
                                         all_memory, wsA, Bdim * Sdim * Hdim / 4);

  // lm = last_memory @ W_w^T   (512x512x512, split-K=4, atomic accumulate)
  gemm_bt<0><<<dim3(Hdim / BN, Bdim / BM, 4), 512, 0, stream>>>(
      wsLast, wsW, Bdim, Hdim, Hdim, wsLm, nullptr, nullptr, nullptr, nullptr);
  // scores += sum_k V[k]*tanh(am + lm)   (25600x512x512), 100 m x 4 n = 400 blocks
  gemm_bt<1><<<dim3((Bdim * Sdim / BM) * (Hdim / BN)), 512, 0, stream>>>(
      wsA, wsU, Bdim * Sdim, Hdim, Hdim, nullptr, wsLm, V_w, wsScores, nullptr);
  softmax_ctx_kernel<<<Bdim, 256, 0, stream>>>(wsScores, mask, wsA, last_memory, wsFeat);
  // out = sigmoid/mask( feat @ E_w^T )   (512x20000x1024), 157 n x 2 m = 314 blocks
  gemm_bt<2><<<dim3(((Ndim + BN - 1) / BN) * (Bdim / BM)), 512, 0, stream>>>(
      wsFeat, wsE, Bdim, Ndim, Kdim2, out, nullptr, nullptr, nullptr, wsSeen);
}

// Round 5
// 131.658 us; speedup vs baseline: 1.3495x; 1.0736x over previous
//
#include <hip/hip_runtime.h>
#include <hip/hip_bf16.h>

#define Bdim 512
#define Sdim 50
#define Hdim 512
#define Ndim 20000
#define Kdim2 1024   // 2*H
#define SEENW 640    // u32 words per row for the seen-bitmask (20000 bits -> 625, pad 640)

typedef __bf16 bf16x8 __attribute__((ext_vector_type(8)));
typedef float f32x4 __attribute__((ext_vector_type(4)));
typedef unsigned short u16;

__device__ __forceinline__ u16 f2bf(float f) {
  unsigned u = __builtin_bit_cast(unsigned, f);
  u = (u + 0x7fffu + ((u >> 16) & 1u)) >> 16;   // RNE
  return (u16)u;
}
__device__ __forceinline__ float bf2f(u16 v) {
  unsigned u = ((unsigned)v) << 16;
  return __builtin_bit_cast(float, u);
}
// HW packed fp32->bf16 (RNE), lo -> [15:0], hi -> [31:16]
__device__ __forceinline__ unsigned cvt_pk_bf16(float lo, float hi) {
  unsigned r;
  asm("v_cvt_pk_bf16_f32 %0, %1, %2" : "=v"(r) : "v"(lo), "v"(hi));
  return r;
}
__device__ __forceinline__ bf16x8 pack8(float4 lo, float4 hi) {
  union { unsigned u[4]; bf16x8 v; } r;
  r.u[0] = cvt_pk_bf16(lo.x, lo.y);
  r.u[1] = cvt_pk_bf16(lo.z, lo.w);
  r.u[2] = cvt_pk_bf16(hi.x, hi.y);
  r.u[3] = cvt_pk_bf16(hi.z, hi.w);
  return r.v;
}

// ---------------- prep: cast last_memory/W_w/U_w + zero scores/lm/seen ----------
// scores/lm are atomic-accumulated and seen is atomicOr'd -> must be zeroed
// EVERY call (graph replays don't re-poison). V_b dropped: softmax is
// shift-invariant, a constant bias on all scores of a row cancels.
__global__ __launch_bounds__(256) void prep_kernel(const float* __restrict__ a, u16* __restrict__ da,
                                                   const float* __restrict__ b, u16* __restrict__ db,
                                                   const float* __restrict__ c, u16* __restrict__ dc,
                                                   float* __restrict__ scores, float* __restrict__ lm,
                                                   unsigned* __restrict__ seen) {
  int i = blockIdx.x * blockDim.x + threadIdx.x;   // 65536 threads, one float4 each
  float4 v; ushort4 o;
  v = reinterpret_cast<const float4*>(a)[i];
  o.x = f2bf(v.x); o.y = f2bf(v.y); o.z = f2bf(v.z); o.w = f2bf(v.w);
  reinterpret_cast<ushort4*>(da)[i] = o;
  v = reinterpret_cast<const float4*>(b)[i];
  o.x = f2bf(v.x); o.y = f2bf(v.y); o.z = f2bf(v.z); o.w = f2bf(v.w);
  reinterpret_cast<ushort4*>(db)[i] = o;
  v = reinterpret_cast<const float4*>(c)[i];
  o.x = f2bf(v.x); o.y = f2bf(v.y); o.z = f2bf(v.z); o.w = f2bf(v.w);
  reinterpret_cast<ushort4*>(dc)[i] = o;
  int stride = gridDim.x * blockDim.x;
  for (int j = i; j < Bdim * Sdim; j += stride) scores[j] = 0.f;
  for (int j = i; j < Bdim * Hdim; j += stride) lm[j] = 0.f;
  for (int j = i; j < Bdim * SEENW; j += stride) seen[j] = 0u;
}

// ---------------- seen-item scatter ----------------
__global__ __launch_bounds__(256) void scatter_kernel(const int* __restrict__ iseq,
                                                      unsigned* __restrict__ seen) {
  int i = blockIdx.x * blockDim.x + threadIdx.x;
  if (i < Bdim * Sdim) {
    int b = i / Sdim;
    int it = iseq[i];
    if (it > 0) atomicOr(&seen[b * SEENW + (it >> 5)], 1u << (it & 31));
  }
}

// ---------------- softmax over S + context readout -> feat (bf16) ----------------
// reads fp32 all_memory directly (no pre-cast copy exists anymore)
__global__ __launch_bounds__(256) void softmax_ctx_kernel(
    const float* __restrict__ scores, const unsigned char* __restrict__ mask,
    const float* __restrict__ amF, const float* __restrict__ last_memory,
    u16* __restrict__ feat) {
  int b = blockIdx.x;
  __shared__ float alpha[Sdim];
  int tid = threadIdx.x;
  if (tid < 64) {
    float s = -1e30f;
    if (tid < Sdim) {
      s = scores[b * Sdim + tid];
      if (mask[b * Sdim + tid]) s = -1e9f;   // mask is all-false in this problem
    }
    float m = s;
#pragma unroll
    for (int off = 32; off; off >>= 1) m = fmaxf(m, __shfl_xor(m, off));
    float e = (tid < Sdim) ? __expf(s - m) : 0.f;
    float sum = e;
#pragma unroll
    for (int off = 32; off; off >>= 1) sum += __shfl_xor(sum, off);
    if (tid < Sdim) alpha[tid] = e / sum;
  }
  __syncthreads();
  for (int h = tid; h < Hdim; h += 256) {
    const float* amp = amF + ((long)b * Sdim) * Hdim + h;
    float c = 0.f;
#pragma unroll 5
    for (int s = 0; s < Sdim; ++s) c += alpha[s] * amp[(long)s * Hdim];
    feat[b * Kdim2 + h] = f2bf(c);
    feat[b * Kdim2 + Hdim + h] = f2bf(last_memory[b * Hdim + h]);
  }
}

// ---------------- MFMA GEMM, B-transposed layout (A: MxK, Bmat: NxK) ----
// 256x128 tile, BK=32, 512 threads = 8 waves (4M x 2N), per-wave 64x64 output.
// 2-phase double-buffered LDS; one __syncthreads per K-step (proven r4 schedule).
// Fused fp32->bf16 staging (kills the standalone cast kernel):
//   EPI 1: A = all_memory fp32, reg-staged (global fp32 float4 loads issued at
//          top of K-step, v_cvt_pk_bf16_f32 + ds_write after MFMA phase = T14)
//   EPI 2: B = E_w fp32, reg-staged the same way
//   bf16 operands use global_load_lds as before.
// Race-safety: buffer written this iteration was last READ one barrier ago.
// EPI 0: atomicAdd f32 into out (lm GEMM), split-K via gridDim.z, 3-D grid
// EPI 1: scores[r] += sum_c V[c]*tanh(acc + lm[b,c]); 1-D grid, XCD swizzle
//        groups the 4 n-tiles of one A m-panel per XCD (A-panel L2 reuse)
// EPI 2: out = seen ? 0 : sigmoid(acc); 1-D grid, XCD swizzle groups the 2
//        m-tiles of one E_w n-panel per XCD (E-panel L2 reuse)
#define BM 256
#define BN 128
#define BK 32

template <int EPI>
__global__ __launch_bounds__(512, 4) void gemm_bt(
    const u16* __restrict__ A, const u16* __restrict__ Bmat,
    const float* __restrict__ Af, const float* __restrict__ Bf,
    int M, int N, int K,
    float* __restrict__ out,
    const float* __restrict__ lm, const float* __restrict__ Vw,
    float* __restrict__ scores, const unsigned* __restrict__ seen) {
  __shared__ bf16x8 Asl[2][BM * BK / 8];   // 2 x 1024 chunks of 16B = 32 KB
  __shared__ bf16x8 Bsl[2][BN * BK / 8];   // 2 x  512 chunks of 16B = 16 KB
  const int tid = threadIdx.x;
  const int lane = tid & 63;
  const int wid = tid >> 6;                 // 0..7
  const int wr = wid >> 1, wc = wid & 1;    // 4x2 wave grid, 64x64 per wave
  const int la = lane & 15, lb = lane >> 4;

  int bx, by, kt0, kt1;
  if constexpr (EPI == 0) {
    bx = blockIdx.x; by = blockIdx.y;
    int ktotal = K / BK; int kper = ktotal / gridDim.z;
    kt0 = blockIdx.z * kper; kt1 = kt0 + kper;
  } else {
    // m204 bijective XCD swizzle: contiguous wgid chunk per XCD; wgid groups
    // co-panel tiles together so panel re-reads are same-XCD L2 hits.
    int nwg = gridDim.x, bid = blockIdx.x;
    int q = nwg >> 3, r = nwg & 7;
    int x = bid & 7, i = bid >> 3;
    int wgid = (x < r ? x * (q + 1) : r * (q + 1) + (x - r) * q) + i;
    if constexpr (EPI == 1) { by = wgid >> 2; bx = wgid & 3; }   // 4 n-tiles/panel
    else                    { bx = wgid >> 1; by = wgid & 1; }   // 2 m-tiles/panel
    kt0 = 0; kt1 = K / BK;
  }
  const int m0 = by * BM;
  const int n0 = bx * BN;

  f32x4 acc[4][4];
  const f32x4 zero = {0.f, 0.f, 0.f, 0.f};
#pragma unroll
  for (int i = 0; i < 4; ++i)
#pragma unroll
    for (int j = 0; j < 4; ++j) acc[i][j] = zero;

  // staging geometry: thread t covers row rw=t>>2 (and 128+rw for A),
  // 8 consecutive k-elements starting at eA=(t&3)*8; chunk index ch=t&3.
  const int rw = tid >> 2;
  const int eA = (tid & 3) * 8;
  const int ch = tid & 3;
  int brB = n0 + rw; if (brB > N - 1) brB = N - 1;   // clamp last n-tile

  const u16 *gA0 = nullptr, *gA1 = nullptr, *gB = nullptr;
  const float *gAf0 = nullptr, *gAf1 = nullptr, *gBf = nullptr;
  if constexpr (EPI == 1) {
    gAf0 = Af + (long)(m0 + rw) * K + eA;
    gAf1 = Af + (long)(m0 + 128 + rw) * K + eA;
  } else {
    gA0 = A + (long)(m0 + rw) * K + eA;
    gA1 = A + (long)(m0 + 128 + rw) * K + eA;
  }
  if constexpr (EPI == 2) {
    gBf = Bf + (long)brB * K + eA;
  } else {
    gB = Bmat + (long)brB * K + eA;
  }

  float4 ra0, ra1, ra2, ra3;   // EPI1: A fp32 staging regs
  float4 rb0, rb1;             // EPI2: B fp32 staging regs

  auto STAGE_G = [&](int buf, int kt) {     // async global->LDS for bf16 operands
    const int k0 = kt * BK;
    if constexpr (EPI != 1) {
      __builtin_amdgcn_global_load_lds((const __attribute__((address_space(1))) void*)(gA0 + k0),
                                       (__attribute__((address_space(3))) void*)(void*)&Asl[buf][wid * 64], 16, 0, 0);
      __builtin_amdgcn_global_load_lds((const __attribute__((address_space(1))) void*)(gA1 + k0),
                                       (__attribute__((address_space(3))) void*)(void*)&Asl[buf][512 + wid * 64], 16, 0, 0);
    }
    if constexpr (EPI != 2) {
      __builtin_amdgcn_global_load_lds((const __attribute__((address_space(1))) void*)(gB + k0),
                                       (__attribute__((address_space(3))) void*)(void*)&Bsl[buf][wid * 64], 16, 0, 0);
    }
  };
  auto LOADR = [&](int kt) {                // issue fp32 reg loads (latency hidden under MFMA)
    const int k0 = kt * BK;
    if constexpr (EPI == 1) {
      ra0 = *reinterpret_cast<const float4*>(gAf0 + k0);
      ra1 = *reinterpret_cast<const float4*>(gAf0 + k0 + 4);
      ra2 = *reinterpret_cast<const float4*>(gAf1 + k0);
      ra3 = *reinterpret_cast<const float4*>(gAf1 + k0 + 4);
    }
    if constexpr (EPI == 2) {
      rb0 = *reinterpret_cast<const float4*>(gBf + k0);
      rb1 = *reinterpret_cast<const float4*>(gBf + k0 + 4);
    }
  };
  auto WRITER = [&](int buf) {              // cvt + ds_write (compiler inserts vmcnt wait)
    if constexpr (EPI == 1) {
      Asl[buf][rw * 4 + ch] = pack8(ra0, ra1);
      Asl[buf][(128 + rw) * 4 + ch] = pack8(ra2, ra3);
    }
    if constexpr (EPI == 2) {
      Bsl[buf][rw * 4 + ch] = pack8(rb0, rb1);
    }
  };

  STAGE_G(0, kt0);
  LOADR(kt0);
  WRITER(0);
  __syncthreads();          // drains vmcnt+lgkm: buf0 fully ready
  int cur = 0;
  for (int kt = kt0; kt < kt1; ++kt) {
    const bool pf = (kt + 1 < kt1);
    if (pf) { STAGE_G(cur ^ 1, kt + 1); LOADR(kt + 1); }   // issue next tile early

    bf16x8 af[4], bfr[4];
#pragma unroll
    for (int mi = 0; mi < 4; ++mi)
      af[mi] = Asl[cur][(wr * 64 + mi * 16 + la) * 4 + lb];   // A[row][k-chunk lb]
#pragma unroll
    for (int ni = 0; ni < 4; ++ni)
      bfr[ni] = Bsl[cur][(wc * 64 + ni * 16 + la) * 4 + lb];  // B[ncol][k-chunk lb]
#pragma unroll
    for (int mi = 0; mi < 4; ++mi)
#pragma unroll
      for (int ni = 0; ni < 4; ++ni)
        acc[mi][ni] = __builtin_amdgcn_mfma_f32_16x16x32_bf16(af[mi], bfr[ni], acc[mi][ni], 0, 0, 0);

    if (pf) WRITER(cur ^ 1);  // fp32 loads have had the whole MFMA phase to land
    __syncthreads();          // one barrier per K-step
    cur ^= 1;
  }

  // C/D layout (verified): col = lane&15, row = (lane>>4)*4 + reg
  if constexpr (EPI == 0) {
#pragma unroll
    for (int mi = 0; mi < 4; ++mi)
#pragma unroll
      for (int i = 0; i < 4; ++i) {
        int r = m0 + wr * 64 + mi * 16 + lb * 4 + i;
#pragma unroll
        for (int ni = 0; ni < 4; ++ni) {
          int c = n0 + wc * 64 + ni * 16 + la;
          atomicAdd(&out[(long)r * N + c], acc[mi][ni][i]);
        }
      }
  }
  if constexpr (EPI == 1) {
#pragma unroll
    for (int mi = 0; mi < 4; ++mi)
#pragma unroll
      for (int i = 0; i < 4; ++i) {
        int r = m0 + wr * 64 + mi * 16 + lb * 4 + i;
        int bidx = r / Sdim;
        float p = 0.f;
#pragma unroll
        for (int ni = 0; ni < 4; ++ni) {
          int c = n0 + wc * 64 + ni * 16 + la;
          float x = acc[mi][ni][i] + lm[bidx * Hdim + c];
          x = fminf(fmaxf(x, -9.f), 9.f);           // tanh saturates; avoid inf/inf
          float e = __expf(2.f * x);
          p += Vw[c] * ((e - 1.f) / (e + 1.f));
        }
        p += __shfl_xor(p, 1);
        p += __shfl_xor(p, 2);
        p += __shfl_xor(p, 4);
        p += __shfl_xor(p, 8);
        if (la == 0) atomicAdd(&scores[r], p);
      }
  }
  if constexpr (EPI == 2) {
#pragma unroll
    for (int mi = 0; mi < 4; ++mi)
#pragma unroll
      for (int i = 0; i < 4; ++i) {
        int r = m0 + wr * 64 + mi * 16 + lb * 4 + i;
        long rb = (long)r * Ndim;
#pragma unroll
        for (int ni = 0; ni < 4; ++ni) {
          int c = n0 + wc * 64 + ni * 16 + la;
          if (c < Ndim) {
            unsigned wbits = seen[r * SEENW + (c >> 5)];
            float val = 0.f;
            if (!((wbits >> (c & 31)) & 1u))
              val = 1.f / (1.f + __expf(-acc[mi][ni][i]));
            out[rb + c] = val;
          }
        }
      }
  }
}

// ---------------- launcher ----------------
extern "C" void kernel_launch(void* const* d_in, const int* in_sizes, int n_in,
                              void* d_out, int out_size, void* d_ws, size_t ws_size,
                              hipStream_t stream) {
  (void)in_sizes; (void)n_in; (void)out_size; (void)ws_size;
  const float* all_memory  = (const float*)d_in[0];
  const float* last_memory = (const float*)d_in[1];
  const int*   item_seq    = (const int*)d_in[2];
  const unsigned char* mask = (const unsigned char*)d_in[3];
  const float* U_w = (const float*)d_in[4];
  const float* W_w = (const float*)d_in[5];
  const float* V_w = (const float*)d_in[6];
  const float* E_w = (const float*)d_in[8];
  float* out = (float*)d_out;

  char* w = (char*)d_ws;
  u16* wsFeat = (u16*)w; w += (size_t)Bdim * Kdim2 * 2;         // 1 MB
  u16* wsLast = (u16*)w; w += (size_t)Hdim * Hdim * 2;          // 0.5 MB
  u16* wsW    = (u16*)w; w += (size_t)Hdim * Hdim * 2;
  u16* wsU    = (u16*)w; w += (size_t)Hdim * Hdim * 2;
  float* wsLm     = (float*)w; w += (size_t)Bdim * Hdim * 4;    // 1 MB
  float* wsScores = (float*)w; w += (size_t)Bdim * Sdim * 4;
  unsigned* wsSeen = (unsigned*)w; w += (size_t)Bdim * SEENW * 4;

  prep_kernel<<<256, 256, 0, stream>>>(last_memory, wsLast, W_w, wsW, U_w, wsU,
                                       wsScores, wsLm, wsSeen);
  scatter_kernel<<<100, 256, 0, stream>>>(item_seq, wsSeen);

  // lm = last_memory @ W_w^T   (512x512x512, split-K=4, atomic accumulate)
  gemm_bt<0><<<dim3(Hdim / BN, Bdim / BM, 4), 512, 0, stream>>>(
      wsLast, wsW, nullptr, nullptr, Bdim, Hdim, Hdim, wsLm,
      nullptr, nullptr, nullptr, nullptr);
  // scores += sum_k V[k]*tanh(am + lm)   (25600x512x512), 100 m x 4 n = 400 blocks
  // A = all_memory fp32, reg-staged with fused cvt
  gemm_bt<1><<<dim3((Bdim * Sdim / BM) * (Hdim / BN)), 512, 0, stream>>>(
      nullptr, wsU, all_memory, nullptr, Bdim * Sdim, Hdim, Hdim, nullptr,
      wsLm, V_w, wsScores, nullptr);
  softmax_ctx_kernel<<<Bdim, 256, 0, stream>>>(wsScores, mask, all_memory, last_memory, wsFeat);
  // out = sigmoid/mask( feat @ E_w^T )   (512x20000x1024), 157 n x 2 m = 314 blocks
  // B = E_w fp32, reg-staged with fused cvt
  gemm_bt<2><<<dim3(((Ndim + BN - 1) / BN) * (Bdim / BM)), 512, 0, stream>>>(
      wsFeat, nullptr, nullptr, E_w, Bdim, Ndim, Kdim2, out,
      nullptr, nullptr, nullptr, wsSeen);
}

// Round 6
// 120.949 us; speedup vs baseline: 1.4689x; 1.0885x over previous
//
#include <hip/hip_runtime.h>
#include <hip/hip_bf16.h>

#define Bdim 512
#define Sdim 50
#define Hdim 512
#define Ndim 20000
#define Kdim2 1024   // 2*H
#define SEENW 640    // u32 words per row for the seen-bitmask (20000 bits -> 625, pad 640)

typedef __bf16 bf16x8 __attribute__((ext_vector_type(8)));
typedef float f32x4 __attribute__((ext_vector_type(4)));
typedef unsigned short u16;

#define AS1 __attribute__((address_space(1)))
#define AS3 __attribute__((address_space(3)))

__device__ __forceinline__ u16 f2bf(float f) {
  unsigned u = __builtin_bit_cast(unsigned, f);
  u = (u + 0x7fffu + ((u >> 16) & 1u)) >> 16;   // RNE
  return (u16)u;
}
__device__ __forceinline__ float bf2f(u16 v) {
  unsigned u = ((unsigned)v) << 16;
  return __builtin_bit_cast(float, u);
}
// HW packed fp32->bf16 (RNE), lo -> [15:0], hi -> [31:16]
__device__ __forceinline__ unsigned cvt_pk_bf16(float lo, float hi) {
  unsigned r;
  asm("v_cvt_pk_bf16_f32 %0, %1, %2" : "=v"(r) : "v"(lo), "v"(hi));
  return r;
}
__device__ __forceinline__ bf16x8 pack8(float4 lo, float4 hi) {
  union { unsigned u[4]; bf16x8 v; } r;
  r.u[0] = cvt_pk_bf16(lo.x, lo.y);
  r.u[1] = cvt_pk_bf16(lo.z, lo.w);
  r.u[2] = cvt_pk_bf16(hi.x, hi.y);
  r.u[3] = cvt_pk_bf16(hi.z, hi.w);
  return r.v;
}

// ---------------- prep: cast last_memory/W_w/U_w + zero scores/lm/seen ----------
__global__ __launch_bounds__(256) void prep_kernel(const float* __restrict__ a, u16* __restrict__ da,
                                                   const float* __restrict__ b, u16* __restrict__ db,
                                                   const float* __restrict__ c, u16* __restrict__ dc,
                                                   float* __restrict__ scores, float* __restrict__ lm,
                                                   unsigned* __restrict__ seen) {
  int i = blockIdx.x * blockDim.x + threadIdx.x;   // 65536 threads, one float4 each
  float4 v; ushort4 o;
  v = reinterpret_cast<const float4*>(a)[i];
  o.x = f2bf(v.x); o.y = f2bf(v.y); o.z = f2bf(v.z); o.w = f2bf(v.w);
  reinterpret_cast<ushort4*>(da)[i] = o;
  v = reinterpret_cast<const float4*>(b)[i];
  o.x = f2bf(v.x); o.y = f2bf(v.y); o.z = f2bf(v.z); o.w = f2bf(v.w);
  reinterpret_cast<ushort4*>(db)[i] = o;
  v = reinterpret_cast<const float4*>(c)[i];
  o.x = f2bf(v.x); o.y = f2bf(v.y); o.z = f2bf(v.z); o.w = f2bf(v.w);
  reinterpret_cast<ushort4*>(dc)[i] = o;
  int stride = gridDim.x * blockDim.x;
  for (int j = i; j < Bdim * Sdim; j += stride) scores[j] = 0.f;
  for (int j = i; j < Bdim * Hdim; j += stride) lm[j] = 0.f;
  for (int j = i; j < Bdim * SEENW; j += stride) seen[j] = 0u;
}

// ---------------- seen-item scatter ----------------
__global__ __launch_bounds__(256) void scatter_kernel(const int* __restrict__ iseq,
                                                      unsigned* __restrict__ seen) {
  int i = blockIdx.x * blockDim.x + threadIdx.x;
  if (i < Bdim * Sdim) {
    int b = i / Sdim;
    int it = iseq[i];
    if (it > 0) atomicOr(&seen[b * SEENW + (it >> 5)], 1u << (it & 31));
  }
}

// ---------------- softmax over S + context readout -> feat (bf16) ----------------
__global__ __launch_bounds__(256) void softmax_ctx_kernel(
    const float* __restrict__ scores, const unsigned char* __restrict__ mask,
    const float* __restrict__ amF, const float* __restrict__ last_memory,
    u16* __restrict__ feat) {
  int b = blockIdx.x;
  __shared__ float alpha[Sdim];
  int tid = threadIdx.x;
  if (tid < 64) {
    float s = -1e30f;
    if (tid < Sdim) {
      s = scores[b * Sdim + tid];
      if (mask[b * Sdim + tid]) s = -1e9f;   // mask is all-false in this problem
    }
    float m = s;
#pragma unroll
    for (int off = 32; off; off >>= 1) m = fmaxf(m, __shfl_xor(m, off));
    float e = (tid < Sdim) ? __expf(s - m) : 0.f;
    float sum = e;
#pragma unroll
    for (int off = 32; off; off >>= 1) sum += __shfl_xor(sum, off);
    if (tid < Sdim) alpha[tid] = e / sum;
  }
  __syncthreads();
  for (int h = tid; h < Hdim; h += 256) {
    const float* amp = amF + ((long)b * Sdim) * Hdim + h;
    float c = 0.f;
#pragma unroll 5
    for (int s = 0; s < Sdim; ++s) c += alpha[s] * amp[(long)s * Hdim];
    feat[b * Kdim2 + h] = f2bf(c);
    feat[b * Kdim2 + Hdim + h] = f2bf(last_memory[b * Hdim + h]);
  }
}

// ---------------- gemm_bt: 2-phase schedule for lm GEMM (EPI0) + scores GEMM (EPI1)
#define BM 256
#define BN 128
#define BK 32

template <int EPI>
__global__ __launch_bounds__(512, 4) void gemm_bt(
    const u16* __restrict__ A, const u16* __restrict__ Bmat,
    const float* __restrict__ Af,
    int M, int N, int K,
    float* __restrict__ out,
    const float* __restrict__ lm, const float* __restrict__ Vw,
    float* __restrict__ scores) {
  __shared__ bf16x8 Asl[2][BM * BK / 8];   // 2 x 1024 chunks of 16B = 32 KB
  __shared__ bf16x8 Bsl[2][BN * BK / 8];   // 2 x  512 chunks of 16B = 16 KB
  const int tid = threadIdx.x;
  const int lane = tid & 63;
  const int wid = tid >> 6;                 // 0..7
  const int wr = wid >> 1, wc = wid & 1;    // 4x2 wave grid, 64x64 per wave
  const int la = lane & 15, lb = lane >> 4;

  int bx, by, kt0, kt1;
  if constexpr (EPI == 0) {
    bx = blockIdx.x; by = blockIdx.y;
    int ktotal = K / BK; int kper = ktotal / gridDim.z;
    kt0 = blockIdx.z * kper; kt1 = kt0 + kper;
  } else {
    int nwg = gridDim.x, bid = blockIdx.x;
    int q = nwg >> 3, r = nwg & 7;
    int x = bid & 7, i = bid >> 3;
    int wgid = (x < r ? x * (q + 1) : r * (q + 1) + (x - r) * q) + i;
    by = wgid >> 2; bx = wgid & 3;          // 4 n-tiles of one A m-panel per XCD
    kt0 = 0; kt1 = K / BK;
  }
  const int m0 = by * BM;
  const int n0 = bx * BN;

  f32x4 acc[4][4];
  const f32x4 zero = {0.f, 0.f, 0.f, 0.f};
#pragma unroll
  for (int i = 0; i < 4; ++i)
#pragma unroll
    for (int j = 0; j < 4; ++j) acc[i][j] = zero;

  const int rw = tid >> 2;
  const int eA = (tid & 3) * 8;
  const int ch = tid & 3;
  int brB = n0 + rw; if (brB > N - 1) brB = N - 1;

  const u16 *gA0 = nullptr, *gA1 = nullptr, *gB = nullptr;
  const float *gAf0 = nullptr, *gAf1 = nullptr;
  if constexpr (EPI == 1) {
    gAf0 = Af + (long)(m0 + rw) * K + eA;
    gAf1 = Af + (long)(m0 + 128 + rw) * K + eA;
  } else {
    gA0 = A + (long)(m0 + rw) * K + eA;
    gA1 = A + (long)(m0 + 128 + rw) * K + eA;
  }
  gB = Bmat + (long)brB * K + eA;

  float4 ra0, ra1, ra2, ra3;   // EPI1: A fp32 staging regs

  auto STAGE_G = [&](int buf, int kt) {
    const int k0 = kt * BK;
    if constexpr (EPI != 1) {
      __builtin_amdgcn_global_load_lds((const AS1 void*)(gA0 + k0),
                                       (AS3 void*)(void*)&Asl[buf][wid * 64], 16, 0, 0);
      __builtin_amdgcn_global_load_lds((const AS1 void*)(gA1 + k0),
                                       (AS3 void*)(void*)&Asl[buf][512 + wid * 64], 16, 0, 0);
    }
    __builtin_amdgcn_global_load_lds((const AS1 void*)(gB + k0),
                                     (AS3 void*)(void*)&Bsl[buf][wid * 64], 16, 0, 0);
  };
  auto LOADR = [&](int kt) {
    const int k0 = kt * BK;
    if constexpr (EPI == 1) {
      ra0 = *reinterpret_cast<const float4*>(gAf0 + k0);
      ra1 = *reinterpret_cast<const float4*>(gAf0 + k0 + 4);
      ra2 = *reinterpret_cast<const float4*>(gAf1 + k0);
      ra3 = *reinterpret_cast<const float4*>(gAf1 + k0 + 4);
    }
  };
  auto WRITER = [&](int buf) {
    if constexpr (EPI == 1) {
      Asl[buf][rw * 4 + ch] = pack8(ra0, ra1);
      Asl[buf][(128 + rw) * 4 + ch] = pack8(ra2, ra3);
    }
  };

  STAGE_G(0, kt0);
  LOADR(kt0);
  WRITER(0);
  __syncthreads();
  int cur = 0;
  for (int kt = kt0; kt < kt1; ++kt) {
    const bool pf = (kt + 1 < kt1);
    if (pf) { STAGE_G(cur ^ 1, kt + 1); LOADR(kt + 1); }

    bf16x8 af[4], bfr[4];
#pragma unroll
    for (int mi = 0; mi < 4; ++mi)
      af[mi] = Asl[cur][(wr * 64 + mi * 16 + la) * 4 + lb];
#pragma unroll
    for (int ni = 0; ni < 4; ++ni)
      bfr[ni] = Bsl[cur][(wc * 64 + ni * 16 + la) * 4 + lb];
#pragma unroll
    for (int mi = 0; mi < 4; ++mi)
#pragma unroll
      for (int ni = 0; ni < 4; ++ni)
        acc[mi][ni] = __builtin_amdgcn_mfma_f32_16x16x32_bf16(af[mi], bfr[ni], acc[mi][ni], 0, 0, 0);

    if (pf) WRITER(cur ^ 1);
    __syncthreads();
    cur ^= 1;
  }

  // C/D layout (verified): col = lane&15, row = (lane>>4)*4 + reg
  if constexpr (EPI == 0) {
#pragma unroll
    for (int mi = 0; mi < 4; ++mi)
#pragma unroll
      for (int i = 0; i < 4; ++i) {
        int r = m0 + wr * 64 + mi * 16 + lb * 4 + i;
#pragma unroll
        for (int ni = 0; ni < 4; ++ni) {
          int c = n0 + wc * 64 + ni * 16 + la;
          atomicAdd(&out[(long)r * N + c], acc[mi][ni][i]);
        }
      }
  }
  if constexpr (EPI == 1) {
#pragma unroll
    for (int mi = 0; mi < 4; ++mi)
#pragma unroll
      for (int i = 0; i < 4; ++i) {
        int r = m0 + wr * 64 + mi * 16 + lb * 4 + i;
        int bidx = r / Sdim;
        float p = 0.f;
#pragma unroll
        for (int ni = 0; ni < 4; ++ni) {
          int c = n0 + wc * 64 + ni * 16 + la;
          float x = acc[mi][ni][i] + lm[bidx * Hdim + c];
          x = fminf(fmaxf(x, -9.f), 9.f);
          float e = __expf(2.f * x);
          p += Vw[c] * ((e - 1.f) / (e + 1.f));
        }
        p += __shfl_xor(p, 1);
        p += __shfl_xor(p, 2);
        p += __shfl_xor(p, 4);
        p += __shfl_xor(p, 8);
        if (la == 0) atomicAdd(&scores[r], p);
      }
  }
}

// ---------------- gemm_logits: deep-pipelined logits GEMM (was EPI2) ----------
// A = feat bf16 [512][1024] via global_load_lds into a 3-slot LDS ring
// (pre-swizzled source). B = E_w fp32 [20000][1024], 2-deep REGISTER pipeline:
// iter kt issues loads for tile kt+2; cvt+ds_write of tile kt+1 happens after
// iter kt's MFMA -> each fp32 load gets ~1 full iteration of latency cover.
// Raw s_barrier + counted s_waitcnt vmcnt(4) (4 vmem ops/wave/iter in flight;
// never drain to 0 in the loop). sched_barrier(0) fences pin issue order so
// in-order vmcnt retirement guarantees A(kt+1) landed when B(kt+1) regs are
// ready (A issued before B each iteration). Register banks are NAMED (no
// dynamic indexing -> no scratch). XOR chunk swizzle (c ^= row&3) on LDS
// kills the 16B-column bank conflicts; gload_lds keeps a LINEAR dest and the
// SOURCE address is pre-swizzled (both-sides rule, m201/m173).
#define LBM 256
#define LBN 128
#define LBK 32

__global__ __launch_bounds__(512, 2) void gemm_logits(
    const u16* __restrict__ A, const float* __restrict__ Bf,
    float* __restrict__ out, const unsigned* __restrict__ seen) {
  __shared__ bf16x8 Asl[3][LBM * LBK / 8];   // 3 x 16 KB
  __shared__ bf16x8 Bsl[2][LBN * LBK / 8];   // 2 x  8 KB
  const int tid = threadIdx.x;
  const int lane = tid & 63;
  const int wid = tid >> 6;
  const int wr = wid >> 1, wc = wid & 1;    // 4x2 waves, 64x64 per wave
  const int la = lane & 15, lb = lane >> 4;
  const int kch = lb ^ (la & 3);            // swizzled k-chunk for LDS reads
  const int K = Kdim2;
  const int NT = K / LBK;                   // 32

  // bijective XCD swizzle; groups the 2 m-tiles of one E_w n-panel per XCD
  int nwg = gridDim.x, bid = blockIdx.x;
  int q = nwg >> 3, r = nwg & 7;
  int x = bid & 7, i0 = bid >> 3;
  int wgid = (x < r ? x * (q + 1) : r * (q + 1) + (x - r) * q) + i0;
  const int bx = wgid >> 1, by = wgid & 1;
  const int m0 = by * LBM, n0 = bx * LBN;

  f32x4 acc[4][4];
  const f32x4 zero = {0.f, 0.f, 0.f, 0.f};
#pragma unroll
  for (int i = 0; i < 4; ++i)
#pragma unroll
    for (int j = 0; j < 4; ++j) acc[i][j] = zero;

  const int rw = tid >> 2;                  // 0..127
  const int ch = tid & 3;
  const int swz = ch ^ (rw & 3);            // pre-swizzled source chunk
  const int chs = swz;                      // swizzled LDS write chunk for B
  int brB = n0 + rw; if (brB > Ndim - 1) brB = Ndim - 1;
  const u16* gA0 = A + (long)(m0 + rw) * K + swz * 8;
  const u16* gA1 = A + (long)(m0 + 128 + rw) * K + swz * 8;
  const float* gBf = Bf + (long)brB * K + ch * 8;

  auto STAGE_A = [&](int kt, int slot) {
    const int k0 = kt * LBK;
    __builtin_amdgcn_global_load_lds((const AS1 void*)(gA0 + k0),
                                     (AS3 void*)(void*)&Asl[slot][wid * 64], 16, 0, 0);
    __builtin_amdgcn_global_load_lds((const AS1 void*)(gA1 + k0),
                                     (AS3 void*)(void*)&Asl[slot][512 + wid * 64], 16, 0, 0);
  };
  auto COMP = [&](int slA, int slB) {
    bf16x8 af[4], bfr[4];
#pragma unroll
    for (int mi = 0; mi < 4; ++mi)
      af[mi] = Asl[slA][(wr * 64 + mi * 16 + la) * 4 + kch];
#pragma unroll
    for (int ni = 0; ni < 4; ++ni)
      bfr[ni] = Bsl[slB][(wc * 64 + ni * 16 + la) * 4 + kch];
#pragma unroll
    for (int mi = 0; mi < 4; ++mi)
#pragma unroll
      for (int ni = 0; ni < 4; ++ni)
        acc[mi][ni] = __builtin_amdgcn_mfma_f32_16x16x32_bf16(af[mi], bfr[ni], acc[mi][ni], 0, 0, 0);
  };

  float4 b0lo, b0hi, b1lo, b1hi;            // 2 named register banks (rule #20)

  // ---- prologue: tiles 0,1 in flight; issue order A(0) B(0) A(1) B(1) ----
  STAGE_A(0, 0);
  __builtin_amdgcn_sched_barrier(0);
  b0lo = *reinterpret_cast<const float4*>(gBf);
  b0hi = *reinterpret_cast<const float4*>(gBf + 4);
  __builtin_amdgcn_sched_barrier(0);
  STAGE_A(1, 1);
  __builtin_amdgcn_sched_barrier(0);
  b1lo = *reinterpret_cast<const float4*>(gBf + LBK);
  b1hi = *reinterpret_cast<const float4*>(gBf + LBK + 4);
  Bsl[0][rw * 4 + chs] = pack8(b0lo, b0hi);      // compiler waits vmcnt for b0
  asm volatile("s_waitcnt vmcnt(4) lgkmcnt(0)" ::: "memory");  // A(0)+ds_write done
  __builtin_amdgcn_sched_barrier(0);
  __builtin_amdgcn_s_barrier();
  __builtin_amdgcn_sched_barrier(0);

  auto ITER = [&](int kt, float4& ldlo, float4& ldhi, float4& stlo, float4& sthi) {
    int tpf = kt + 2; if (tpf > NT - 1) tpf = NT - 1;   // uniform 4 loads/iter
    STAGE_A(tpf, (kt + 2) % 3);
    __builtin_amdgcn_sched_barrier(0);       // A before B: in-order retire proof
    ldlo = *reinterpret_cast<const float4*>(gBf + tpf * LBK);
    ldhi = *reinterpret_cast<const float4*>(gBf + tpf * LBK + 4);
    COMP(kt % 3, kt & 1);
    Bsl[(kt + 1) & 1][rw * 4 + chs] = pack8(stlo, sthi);  // tile kt+1 -> LDS
    asm volatile("s_waitcnt vmcnt(4) lgkmcnt(0)" ::: "memory");
    __builtin_amdgcn_sched_barrier(0);
    __builtin_amdgcn_s_barrier();            // slot kt+1 (A and B) ready
    __builtin_amdgcn_sched_barrier(0);
  };

  for (int kt = 0; kt < NT; kt += 2) {
    ITER(kt,     b0lo, b0hi, b1lo, b1hi);    // load bank0, store bank1
    ITER(kt + 1, b1lo, b1hi, b0lo, b0hi);    // load bank1, store bank0
  }

  // epilogue: sigmoid + seen-mask
#pragma unroll
  for (int mi = 0; mi < 4; ++mi)
#pragma unroll
    for (int i = 0; i < 4; ++i) {
      int r = m0 + wr * 64 + mi * 16 + lb * 4 + i;
      long rb = (long)r * Ndim;
#pragma unroll
      for (int ni = 0; ni < 4; ++ni) {
        int c = n0 + wc * 64 + ni * 16 + la;
        if (c < Ndim) {
          unsigned wbits = seen[r * SEENW + (c >> 5)];
          float val = 0.f;
          if (!((wbits >> (c & 31)) & 1u))
            val = 1.f / (1.f + __expf(-acc[mi][ni][i]));
          out[rb + c] = val;
        }
      }
    }
}

// ---------------- launcher ----------------
extern "C" void kernel_launch(void* const* d_in, const int* in_sizes, int n_in,
                              void* d_out, int out_size, void* d_ws, size_t ws_size,
                              hipStream_t stream) {
  (void)in_sizes; (void)n_in; (void)out_size; (void)ws_size;
  const float* all_memory  = (const float*)d_in[0];
  const float* last_memory = (const float*)d_in[1];
  const int*   item_seq    = (const int*)d_in[2];
  const unsigned char* mask = (const unsigned char*)d_in[3];
  const float* U_w = (const float*)d_in[4];
  const float* W_w = (const float*)d_in[5];
  const float* V_w = (const float*)d_in[6];
  const float* E_w = (const float*)d_in[8];
  float* out = (float*)d_out;

  char* w = (char*)d_ws;
  u16* wsFeat = (u16*)w; w += (size_t)Bdim * Kdim2 * 2;         // 1 MB
  u16* wsLast = (u16*)w; w += (size_t)Hdim * Hdim * 2;          // 0.5 MB
  u16* wsW    = (u16*)w; w += (size_t)Hdim * Hdim * 2;
  u16* wsU    = (u16*)w; w += (size_t)Hdim * Hdim * 2;
  float* wsLm     = (float*)w; w += (size_t)Bdim * Hdim * 4;    // 1 MB
  float* wsScores = (float*)w; w += (size_t)Bdim * Sdim * 4;
  unsigned* wsSeen = (unsigned*)w; w += (size_t)Bdim * SEENW * 4;

  prep_kernel<<<256, 256, 0, stream>>>(last_memory, wsLast, W_w, wsW, U_w, wsU,
                                       wsScores, wsLm, wsSeen);
  scatter_kernel<<<100, 256, 0, stream>>>(item_seq, wsSeen);

  // lm = last_memory @ W_w^T   (512x512x512, split-K=4, atomic accumulate)
  gemm_bt<0><<<dim3(Hdim / BN, Bdim / BM, 4), 512, 0, stream>>>(
      wsLast, wsW, nullptr, Bdim, Hdim, Hdim, wsLm, nullptr, nullptr, nullptr);
  // scores += sum_k V[k]*tanh(am + lm)   (25600x512x512), 100 m x 4 n = 400 blocks
  gemm_bt<1><<<dim3((Bdim * Sdim / BM) * (Hdim / BN)), 512, 0, stream>>>(
      nullptr, wsU, all_memory, Bdim * Sdim, Hdim, Hdim, nullptr,
      wsLm, V_w, wsScores);
  softmax_ctx_kernel<<<Bdim, 256, 0, stream>>>(wsScores, mask, all_memory, last_memory, wsFeat);
  // out = sigmoid/mask( feat @ E_w^T )   (512x20000x1024), 157 n x 2 m = 314 blocks
  gemm_logits<<<dim3(((Ndim + LBN - 1) / LBN) * (Bdim / LBM)), 512, 0, stream>>>(
      wsFeat, E_w, out, wsSeen);
}